// Round 6
// baseline (257.750 us; speedup 1.0000x reference)
//
#include <hip/hip_runtime.h>
#include <stdint.h>

// ---------------------------------------------------------------------------
// BertSelfAttention (relative_key_query) on gfx950.
// B=4 S=1024 H=768 nH=12 dH=64 MAXPOS=1024.
// R6: attn restructured — NO global_load_lds (k/v/E direct global->register,
// L2-hot; no vmcnt drain at barriers), ONE barrier/iter (keb parity dbuf),
// unsheared keb[t][j] (vector u32 producer, <=2-way banks both sides),
// XCD swizzle for k/v L2 residency. qkv/convert unchanged from R5.
// ---------------------------------------------------------------------------

typedef __attribute__((ext_vector_type(4))) float f32x4;
typedef __attribute__((ext_vector_type(8))) short s16x8;
typedef const __attribute__((address_space(1))) void GCV;
typedef __attribute__((address_space(3))) void LDSV;

__device__ __forceinline__ unsigned short f2bf(float f) {
  union { float f; uint32_t u; } v; v.f = f;
  uint32_t r = (v.u + 0x7FFFu + ((v.u >> 16) & 1u)) >> 16;
  return (unsigned short)r;
}
__device__ __forceinline__ float bf2f(unsigned short b) {
  union { uint32_t u; float f; } v; v.u = ((uint32_t)b) << 16;
  return v.f;
}
__device__ __forceinline__ uint32_t pack2(float a, float b) {
  return (uint32_t)f2bf(a) | ((uint32_t)f2bf(b) << 16);
}

#define MFMA(a, b, c) __builtin_amdgcn_mfma_f32_16x16x32_bf16((a), (b), (c), 0, 0, 0)

// ---------------------------------------------------------------------------
// Kernel 0: fp32 -> bf16 conversion.
// ---------------------------------------------------------------------------
#define HIDQ 786432   // 4096*768/4
#define WQ4  147456   // 768*768/4

__global__ __launch_bounds__(256) void convert_kernel(
    const float* __restrict__ hid, const float* __restrict__ wq,
    const float* __restrict__ wk, const float* __restrict__ wv,
    const float* __restrict__ de,
    unsigned short* __restrict__ hidbf, unsigned short* __restrict__ wbf,
    unsigned short* __restrict__ ebf) {
  int g = blockIdx.x * 256 + threadIdx.x;
  if (g < HIDQ) {
    float4 s = ((const float4*)hid)[g];
    ushort4 o; o.x = f2bf(s.x); o.y = f2bf(s.y); o.z = f2bf(s.z); o.w = f2bf(s.w);
    ((ushort4*)hidbf)[g] = o;
  } else if (g < HIDQ + 3 * WQ4) {
    int r = g - HIDQ;
    int sel = r / WQ4, r2 = r - sel * WQ4;
    const float* src = sel == 0 ? wq : (sel == 1 ? wk : wv);
    float4 s = ((const float4*)src)[r2];
    ushort4 o; o.x = f2bf(s.x); o.y = f2bf(s.y); o.z = f2bf(s.z); o.w = f2bf(s.w);
    ((ushort4*)wbf)[r] = o;
  } else {
    int r = g - HIDQ - 3 * WQ4;      // [0, 32768)
    int e = 4 * r;
    ushort4 o;
    o.x = (e + 0 < 131008) ? f2bf(de[e + 0]) : 0;
    o.y = (e + 1 < 131008) ? f2bf(de[e + 1]) : 0;
    o.z = (e + 2 < 131008) ? f2bf(de[e + 2]) : 0;
    o.w = (e + 3 < 131008) ? f2bf(de[e + 3]) : 0;
    ((ushort4*)ebf)[r] = o;
  }
}

// ---------------------------------------------------------------------------
// Kernel 1: QKV GEMM, double-buffered (unchanged from R5, passing).
// ---------------------------------------------------------------------------
__global__ __launch_bounds__(256, 2) void qkv_gemm(
    const unsigned short* __restrict__ hidbf,   // [4096][768]
    const unsigned short* __restrict__ wbf,     // [3][768][768]
    const float* __restrict__ bq, const float* __restrict__ bk,
    const float* __restrict__ bv,
    unsigned short* __restrict__ qb, unsigned short* __restrict__ kb,
    unsigned short* __restrict__ vtb) {
  __shared__ union {
    struct { unsigned short a[2][8192]; unsigned short b[2][8192]; } s;  // 64KB
    unsigned short cw[128 * 136];                                        // 34.8KB
  } sm;
  const int tid = threadIdx.x;
  const int w = tid >> 6, lane = tid & 63, quad = lane >> 4, l15 = lane & 15;
  const int m0 = blockIdx.x * 128;
  const int bn = blockIdx.y;
  const int sel = bn / 6;
  const int nc0 = (bn - sel * 6) * 128;
  const unsigned short* wsrc = wbf + (size_t)sel * 589824;

  f32x4 acc[4][4];
#pragma unroll
  for (int i = 0; i < 4; ++i)
#pragma unroll
    for (int j = 0; j < 4; ++j) acc[i][j] = (f32x4){0.f, 0.f, 0.f, 0.f};

  const int rA = 64 * (w & 1);
  const int rB = 64 * (w >> 1);
  int scl = w * 4;

#pragma unroll
  for (int i = 0; i < 4; ++i) {
    int cl = (scl + i) * 64 + lane;
    int row = cl >> 3, cp = cl & 7, gch = cp ^ (row & 7);
    __builtin_amdgcn_global_load_lds((GCV*)(hidbf + (size_t)(m0 + row) * 768 + gch * 8),
                                     (LDSV*)(sm.s.a[0] + (size_t)(scl + i) * 512), 16, 0, 0);
    __builtin_amdgcn_global_load_lds((GCV*)(wsrc + (size_t)(nc0 + row) * 768 + gch * 8),
                                     (LDSV*)(sm.s.b[0] + (size_t)(scl + i) * 512), 16, 0, 0);
  }

  for (int kit = 0; kit < 12; ++kit) {
    const int cur = kit & 1;
    __syncthreads();
    if (kit + 1 < 12) {
      int k0 = (kit + 1) * 64, nxt = cur ^ 1;
#pragma unroll
      for (int i = 0; i < 4; ++i) {
        int cl = (scl + i) * 64 + lane;
        int row = cl >> 3, cp = cl & 7, gch = cp ^ (row & 7);
        __builtin_amdgcn_global_load_lds(
            (GCV*)(hidbf + (size_t)(m0 + row) * 768 + k0 + gch * 8),
            (LDSV*)(sm.s.a[nxt] + (size_t)(scl + i) * 512), 16, 0, 0);
        __builtin_amdgcn_global_load_lds(
            (GCV*)(wsrc + (size_t)(nc0 + row) * 768 + k0 + gch * 8),
            (LDSV*)(sm.s.b[nxt] + (size_t)(scl + i) * 512), 16, 0, 0);
      }
    }
    s16x8 af[4][2], bfr[4][2];
#pragma unroll
    for (int mt = 0; mt < 4; ++mt)
#pragma unroll
      for (int ks = 0; ks < 2; ++ks) {
        int row = rA + 16 * mt + l15;
        af[mt][ks] = *(const s16x8*)(sm.s.a[cur] + row * 64 + (((quad + 4 * ks) ^ (row & 7)) * 8));
        int rowb = rB + 16 * mt + l15;
        bfr[mt][ks] = *(const s16x8*)(sm.s.b[cur] + rowb * 64 + (((quad + 4 * ks) ^ (rowb & 7)) * 8));
      }
#pragma unroll
    for (int mt = 0; mt < 4; ++mt)
#pragma unroll
      for (int nt = 0; nt < 4; ++nt) {
        acc[mt][nt] = MFMA(af[mt][0], bfr[nt][0], acc[mt][nt]);
        acc[mt][nt] = MFMA(af[mt][1], bfr[nt][1], acc[mt][nt]);
      }
  }
  __syncthreads();

  const float* bias = sel == 0 ? bq : (sel == 1 ? bk : bv);
  if (sel < 2) {
#pragma unroll
    for (int nt = 0; nt < 4; ++nt) {
      int ocl = rB + 16 * nt + l15;
      float bvl = bias[nc0 + ocl];
#pragma unroll
      for (int mt = 0; mt < 4; ++mt) {
        int ml = rA + 16 * mt + 4 * quad;
#pragma unroll
        for (int r = 0; r < 4; ++r)
          sm.cw[(ml + r) * 136 + ocl] = f2bf(acc[mt][nt][r] + bvl);
      }
    }
    __syncthreads();
    int sl = tid & 127, hd = tid >> 7;
    int m = m0 + sl, bb = m >> 10, s = m & 1023;
    int hh = (nc0 + hd * 64) >> 6;
    unsigned short* dst = (sel == 0 ? qb : kb) + (size_t)(bb * 12 + hh) * 65536 + (size_t)s * 64;
    const unsigned short* srcr = sm.cw + sl * 136 + hd * 64;
#pragma unroll
    for (int c = 0; c < 8; ++c)
      *(s16x8*)(dst + c * 8) = *(const s16x8*)(srcr + c * 8);
  } else {
#pragma unroll
    for (int nt = 0; nt < 4; ++nt) {
      int oc = nc0 + rB + 16 * nt + l15;
      float bvl = bias[oc];
      int h = oc >> 6, dd = oc & 63;
#pragma unroll
      for (int mt = 0; mt < 4; ++mt) {
        int mbase = m0 + rA + 16 * mt + quad * 4;
        int bb = mbase >> 10, s = mbase & 1023;
        ushort4 pk;
        pk.x = f2bf(acc[mt][nt][0] + bvl); pk.y = f2bf(acc[mt][nt][1] + bvl);
        pk.z = f2bf(acc[mt][nt][2] + bvl); pk.w = f2bf(acc[mt][nt][3] + bvl);
        *(ushort4*)(vtb + (size_t)(bb * 12 + h) * 65536 + (size_t)dd * 1024 + s) = pk;
      }
    }
  }
}

// ---------------------------------------------------------------------------
// Kernel 2: fused attention, R6. Block = (bh, 64 q-rows); wave w = i-strip
// [16w,16w+16). NO LDS staging of k/v/E — plain global loads into registers
// (L2-hot; waits placed at use, not at barriers). LDS only for the shear:
//   keb[2][t 128][j 64] stride 70, parity dbuf: Ke[t][j] = k_j.E[dbase+t]
//     producer: u32 pair writes (<=2-way banks); consumer: scalar (<=2-way)
//   qet[w][t' 80][i' 16] stride 18: per-wave Qe; P aliases region, stride 72.
// ONE __syncthreads per iter. Race audit (barrier = mid-iter D only):
//   (e:i) reads keb[i&1]; (c:i+1) writes keb[(i+1)&1] — disjoint.
//   (c:i+2) rewrites keb[i&1]: any wave there passed D(i+1), and every wave
//   passed its (e:i) reads before D(i+1). qet/P strictly own-wave (lgkmcnt).
// XCD swizzle: bh = (blk&7)+8*(slot>>4) — all 16 l-tiles of a bh on one XCD.
// LDS 46.25KB -> 3 blocks/CU at launch_bounds(256,3); VGPR ~145 fits 168 cap.
// ---------------------------------------------------------------------------
__global__ __launch_bounds__(256, 3) void attn_kernel(
    const unsigned short* __restrict__ qb, const unsigned short* __restrict__ kb,
    const unsigned short* __restrict__ vtb, const unsigned short* __restrict__ ebf,
    const float* __restrict__ mask, float* __restrict__ out) {
  __shared__ unsigned short keb[2][128 * 70];    // 35KB parity dbuf
  __shared__ unsigned short qet[4][1440];        // 11.25KB per-wave Qe / P

  const int tid = threadIdx.x;
  const int w = tid >> 6, lane = tid & 63, quad = lane >> 4, l15 = lane & 15;
  const int xcd = blockIdx.x & 7, slot = blockIdx.x >> 3;
  const int bh = xcd + 8 * (slot >> 4);          // 48 bh = 8 XCD x 6
  const int l0 = (slot & 15) << 6;
  const int b = bh / 12;
  const int h = bh - b * 12;

  // q B-frags for strip row l0+16w+l15 (held all 16 iters)
  const unsigned short* qrow = qb + (size_t)bh * 65536 + (size_t)(l0 + 16 * w + l15) * 64;
  s16x8 qf[2];
  qf[0] = *(const s16x8*)(qrow + quad * 8);
  qf[1] = *(const s16x8*)(qrow + 32 + quad * 8);

  f32x4 oacc[4];
#pragma unroll
  for (int i = 0; i < 4; ++i) oacc[i] = (f32x4){0.f, 0.f, 0.f, 0.f};
  float lsum = 0.f;
  const float SC1 = 0.18033688f;   // log2(e)/8
  const float SC2 = 1.44269504f;   // log2(e)

  const unsigned short* kbh = kb + (size_t)bh * 65536;
  const unsigned short* vbh = vtb + (size_t)bh * 65536;
  unsigned short* qetW = &qet[w][0];

  // Ke tile ownership: bit (w*4+mt) of KETv[tp] -> wave w computes tile
  // (tt=w+tp, mt). Covers exactly the 20 tiles with tt+mt in [3,7], 5/wave.
  const uint32_t KETv[5] = {0x0008, 0x008C, 0x6FF6, 0x3100, 0x1000};

  for (int it = 0; it < 16; ++it) {
    const int r0 = it << 6;
    const int dbase = l0 - r0 + 960;             // global E row of t=0
    unsigned short* kebC = &keb[it & 1][0];

    // ---- (a) k A-frags direct from global (coalesced dwordx4, L2-hot)
    s16x8 kf[4][2];
    const unsigned short* kbit = kbh + (size_t)r0 * 64;
#pragma unroll
    for (int mt = 0; mt < 4; ++mt) {
      const unsigned short* kr = kbit + (size_t)(16 * mt + l15) * 64;
      kf[mt][0] = *(const s16x8*)(kr + quad * 8);
      kf[mt][1] = *(const s16x8*)(kr + 32 + quad * 8);
    }

    // ---- (b) St[j][i'] = k . q
    f32x4 st[4];
#pragma unroll
    for (int mt = 0; mt < 4; ++mt) {
      f32x4 a = (f32x4){0.f, 0.f, 0.f, 0.f};
      a = MFMA(kf[mt][0], qf[0], a);
      a = MFMA(kf[mt][1], qf[1], a);
      st[mt] = a;
    }

    // ---- (c) E direct loads; Qe -> qet; Ke (owned tiles) -> keb[it&1]
#pragma unroll
    for (int tp = 0; tp < 5; ++tp) {
      const unsigned short* er = ebf + (size_t)(dbase + 16 * (w + tp) + l15) * 64;
      s16x8 ef0 = *(const s16x8*)(er + quad * 8);
      s16x8 ef1 = *(const s16x8*)(er + 32 + quad * 8);
      f32x4 a = (f32x4){0.f, 0.f, 0.f, 0.f};
      a = MFMA(qf[0], ef0, a);
      a = MFMA(qf[1], ef1, a);
      {  // Qe[t'row = 16tp+l15][i' = 4quad+r], stride 18, u32 pairs
        int e = (16 * tp + l15) * 18 + 4 * quad;
        *(uint32_t*)(qetW + e) = pack2(a[0], a[1]);
        *(uint32_t*)(qetW + e + 2) = pack2(a[2], a[3]);
      }
      uint32_t km = (KETv[tp] >> (w * 4)) & 15;
      int tpr = 16 * (w + tp) + l15;             // block-local t
#pragma unroll
      for (int mt = 0; mt < 4; ++mt) {
        if ((km >> mt) & 1) {
          f32x4 ka = (f32x4){0.f, 0.f, 0.f, 0.f};
          ka = MFMA(kf[mt][0], ef0, ka);
          ka = MFMA(kf[mt][1], ef1, ka);
          int e = tpr * 70 + 16 * mt + 4 * quad; // unsheared [t][j], u32 pairs
          *(uint32_t*)(kebC + e) = pack2(ka[0], ka[1]);
          *(uint32_t*)(kebC + e + 2) = pack2(ka[2], ka[3]);
        }
      }
    }
    __syncthreads();   // barrier D: keb[it&1] ready (no vmem-LDS drain needed)

    // ---- (e) v B-frags direct from global (issued early, used after gathers)
    s16x8 vf[4][2];
    const unsigned short* vbit = vbh + r0;
#pragma unroll
    for (int dt = 0; dt < 4; ++dt) {
      const unsigned short* vr = vbit + (size_t)(16 * dt + l15) * 1024;
      vf[dt][0] = *(const s16x8*)(vr + quad * 8);
      vf[dt][1] = *(const s16x8*)(vr + 32 + quad * 8);
    }

    // softmax: diagonal gathers (bank-clean scalar), max-free exp
    const float* mrow = mask + b * 1024 + r0;
    float pv4[4][4];
#pragma unroll
    for (int mt = 0; mt < 4; ++mt) {
      float4 m4 = *(const float4*)(mrow + 16 * mt + 4 * quad);
#pragma unroll
      for (int r = 0; r < 4; ++r) {
        int j = 16 * mt + 4 * quad + r;
        float qv = bf2f(qetW[(l15 - j + 63) * 18 + l15]);
        float kv = bf2f(kebC[(16 * w + l15 - j + 63) * 70 + j]);
        float p = __builtin_amdgcn_exp2f((st[mt][r] + qv + kv) * SC1 + (&m4.x)[r] * SC2);
        pv4[mt][r] = p;
        lsum += p;
      }
    }
    // P[i'=l15][j] stride 72 (aliases qet; own-wave, written after all gathers)
#pragma unroll
    for (int mt = 0; mt < 4; ++mt) {
      int e = l15 * 72 + 16 * mt + 4 * quad;
      *(uint2*)(qetW + e) = (uint2){pack2(pv4[mt][0], pv4[mt][1]),
                                    pack2(pv4[mt][2], pv4[mt][3])};
    }
    s16x8 pf0 = *(const s16x8*)(qetW + l15 * 72 + quad * 8);
    s16x8 pf1 = *(const s16x8*)(qetW + l15 * 72 + 32 + quad * 8);

    // O += P @ V
#pragma unroll
    for (int dt = 0; dt < 4; ++dt) {
      oacc[dt] = MFMA(pf0, vf[dt][0], oacc[dt]);
      oacc[dt] = MFMA(pf1, vf[dt][1], oacc[dt]);
    }
  }

  // ---- finalize: per-lane row sums (i'=l15); combine quads, divide, store
  lsum += __shfl_xor(lsum, 16, 64);
  lsum += __shfl_xor(lsum, 32, 64);
#pragma unroll
  for (int r = 0; r < 4; ++r) {
    float ls = __shfl(lsum, quad * 4 + r, 64);
    float rinv = 1.0f / ls;
    int l = l0 + 16 * w + quad * 4 + r;
    float* dst = out + ((size_t)(b * 1024 + l)) * 768 + h * 64;
#pragma unroll
    for (int dt = 0; dt < 4; ++dt) dst[16 * dt + l15] = oacc[dt][r] * rinv;
  }
}

// ---------------------------------------------------------------------------
extern "C" void kernel_launch(void* const* d_in, const int* in_sizes, int n_in,
                              void* d_out, int out_size, void* d_ws, size_t ws_size,
                              hipStream_t stream) {
  const float* hid  = (const float*)d_in[0];
  const float* mask = (const float*)d_in[1];
  const float* wq   = (const float*)d_in[2];
  const float* bq   = (const float*)d_in[3];
  const float* wk   = (const float*)d_in[4];
  const float* bk   = (const float*)d_in[5];
  const float* wv   = (const float*)d_in[6];
  const float* bv   = (const float*)d_in[7];
  const float* de   = (const float*)d_in[8];

  char* ws = (char*)d_ws;
  unsigned short* hidbf = (unsigned short*)(ws);                  // 6,291,456 B
  unsigned short* wbf   = (unsigned short*)(ws + 6291456);        // 3,538,944 B
  unsigned short* ebf   = (unsigned short*)(ws + 9830400);        //   262,144 B
  unsigned short* qb    = (unsigned short*)(ws + 10092544);       // 6,291,456 B
  unsigned short* kb    = (unsigned short*)(ws + 16384000);       // 6,291,456 B
  unsigned short* vtb   = (unsigned short*)(ws + 22675456);       // 6,291,456 B

  convert_kernel<<<4928, 256, 0, stream>>>(hid, wq, wk, wv, de, hidbf, wbf, ebf);
  qkv_gemm<<<dim3(32, 18), 256, 0, stream>>>(hidbf, wbf, bq, bk, bv, qb, kb, vtb);
  attn_kernel<<<768, 256, 0, stream>>>(qb, kb, vtb, ebf, mask, (float*)d_out);
}